// Round 3
// baseline (108.465 us; speedup 1.0000x reference)
//
#include <hip/hip_runtime.h>
#include <limits.h>

#define ID_MAX 4096

typedef float vf4 __attribute__((ext_vector_type(4)));

// ---------------------------------------------------------------------------
// K1: one block per graph. Build first-occurrence table in LDS (atomicMin on
// LDS, not global), flush to global table[b*ID_MAX..], and zero graph_out.
// Replaces init_kernel + build_table_kernel (one launch instead of two,
// no global atomics).
// ---------------------------------------------------------------------------
__global__ void build_table_fused(const int* __restrict__ node_index,
                                  const int* __restrict__ ptr,
                                  int* __restrict__ table,
                                  float* __restrict__ graph_out,
                                  int D) {
    __shared__ int ltab[ID_MAX];
    const int b   = blockIdx.x;
    const int tid = threadIdx.x;
    const int start = ptr[b];
    const int end   = ptr[b + 1];

    for (int i = tid; i < ID_MAX; i += blockDim.x) ltab[i] = INT_MAX;
    __syncthreads();

    for (int i = start + tid; i < end; i += blockDim.x) {
        int id = node_index[i];
        if (id >= 0 && id < ID_MAX)
            atomicMin(&ltab[id], i - start);   // local position in graph b
    }
    __syncthreads();

    int* gt = table + (size_t)b * ID_MAX;
    for (int i = tid; i < ID_MAX; i += blockDim.x) gt[i] = ltab[i];

    float* go = graph_out + (size_t)b * D;
    for (int i = tid; i < D; i += blockDim.x) go[i] = 0.0f;
}

__device__ __forceinline__ int seg_search(const int* sptr, int B, int i) {
    if (i < sptr[0] || i >= sptr[B]) return -1;
    int lo = 0, hi = B;
    while (hi - lo > 1) {
        int mid = (lo + hi) >> 1;
        if (sptr[mid] <= i) lo = mid; else hi = mid;
    }
    return lo;
}

// ---------------------------------------------------------------------------
// K2: fused pool + gather in one grid so the two independent memory streams
// co-execute (stream-captured graphs serialize separate launches).
//   blocks [0, pool_blocks)          : segment-sum pool (float4, NT loads)
//   blocks [pool_blocks, ...)        : table-lookup gather (float4, NT stores)
// ---------------------------------------------------------------------------
__global__ void pool_gather_fused(const vf4* __restrict__ x4,
                                  const int* __restrict__ ptr,
                                  const int* __restrict__ input_ids,
                                  const int* __restrict__ table,
                                  float* __restrict__ graph_out,
                                  vf4* __restrict__ out4,
                                  int N, int B, int D, int vpr, int vshift, int L,
                                  int pool_blocks, int rows_pb,
                                  long long total_vec) {
    const int tid = threadIdx.x;

    if ((int)blockIdx.x < pool_blocks) {
        // ---------------- pool ----------------
        __shared__ int sptr[64];
        __shared__ vf4 red[256];
        if (tid <= B) sptr[tid] = ptr[tid];
        __syncthreads();

        const int rows_per_iter = 256 / vpr;   // vpr divides 256 (host-checked)
        const int c    = tid & (vpr - 1);
        const int rsub = tid / vpr;

        const int r0 = blockIdx.x * rows_pb;
        const int r1 = min(r0 + rows_pb, N);
        if (r0 >= r1) return;

        const int b_first = seg_search(sptr, B, r0);
        const int b_last  = seg_search(sptr, B, r1 - 1);

        if (b_first == b_last && b_first >= 0) {
            // fast path: whole chunk inside one graph -> pure streaming
            vf4 acc = 0.0f;
            for (int i = r0 + rsub; i < r1; i += rows_per_iter)
                acc += __builtin_nontemporal_load(&x4[(size_t)i * vpr + c]);
            red[tid] = acc;
            __syncthreads();
            if (rsub == 0) {
                for (int k = 1; k < rows_per_iter; ++k)
                    acc += red[k * vpr + c];
                float* dst = &graph_out[(size_t)b_first * D + c * 4];
                atomicAdd(dst + 0, acc.x);
                atomicAdd(dst + 1, acc.y);
                atomicAdd(dst + 2, acc.z);
                atomicAdd(dst + 3, acc.w);
            }
        } else {
            // generic path: chunk crosses a boundary (rare)
            vf4 acc = 0.0f;
            int accb = -1;
            for (int i = r0 + rsub; i < r1; i += rows_per_iter) {
                int b = seg_search(sptr, B, i);
                if (b != accb) {
                    if (accb >= 0) {
                        float* dst = &graph_out[(size_t)accb * D + c * 4];
                        atomicAdd(dst + 0, acc.x);
                        atomicAdd(dst + 1, acc.y);
                        atomicAdd(dst + 2, acc.z);
                        atomicAdd(dst + 3, acc.w);
                    }
                    acc = 0.0f;
                    accb = b;
                }
                if (b >= 0) acc += x4[(size_t)i * vpr + c];
            }
            if (accb >= 0) {
                float* dst = &graph_out[(size_t)accb * D + c * 4];
                atomicAdd(dst + 0, acc.x);
                atomicAdd(dst + 1, acc.y);
                atomicAdd(dst + 2, acc.z);
                atomicAdd(dst + 3, acc.w);
            }
        }
    } else {
        // ---------------- gather ----------------
        long long t = (long long)(blockIdx.x - pool_blocks) * blockDim.x + tid;
        if (t >= total_vec) return;
        int row = (int)(t >> vshift);          // flattened (b,l)
        int c   = (int)(t & (vpr - 1));
        int b   = row / L;
        int id  = input_ids[row];
        int m   = (id >= 0 && id < ID_MAX) ? table[(size_t)b * ID_MAX + id]
                                           : INT_MAX;
        vf4 v = 0.0f;
        if (m != INT_MAX)
            v = x4[(long long)m * vpr + c];    // row m used GLOBALLY (faithful
                                               // to reference's local-as-global quirk)
        __builtin_nontemporal_store(v, &out4[t]);
    }
}

// ---------------------------------------------------------------------------
// Fallback kernels (odd D etc.) — previous round's generic path
// ---------------------------------------------------------------------------
__global__ void init_kernel(int* __restrict__ table, float* __restrict__ graph_out,
                            int table_n, int graph_n) {
    int i = blockIdx.x * blockDim.x + threadIdx.x;
    if (i < table_n) table[i] = INT_MAX;
    if (i < graph_n) graph_out[i] = 0.0f;
}

__global__ void build_table_kernel(const int* __restrict__ node_index,
                                   const int* __restrict__ ptr,
                                   int* __restrict__ table, int N, int B) {
    __shared__ int sptr[64];
    if (threadIdx.x <= B) sptr[threadIdx.x] = ptr[threadIdx.x];
    __syncthreads();
    int i = blockIdx.x * blockDim.x + threadIdx.x;
    if (i >= N) return;
    int b = seg_search(sptr, B, i);
    if (b < 0) return;
    int m = i - sptr[b];
    int id = node_index[i];
    if (id >= 0 && id < ID_MAX)
        atomicMin(&table[b * ID_MAX + id], m);
}

__global__ void pool1_kernel(const float* __restrict__ x,
                             const int* __restrict__ ptr,
                             float* __restrict__ graph_out,
                             int N, int B, int D, int rows_per_block) {
    __shared__ int sptr[64];
    if (threadIdx.x <= B) sptr[threadIdx.x] = ptr[threadIdx.x];
    __syncthreads();
    int d = threadIdx.x;
    if (d >= D) return;
    int r0 = blockIdx.x * rows_per_block;
    int r1 = min(r0 + rows_per_block, N);
    float acc = 0.0f;
    int accb = -1;
    for (int i = r0; i < r1; ++i) {
        int b = seg_search(sptr, B, i);
        if (b != accb) {
            if (accb >= 0) atomicAdd(&graph_out[(size_t)accb * D + d], acc);
            acc = 0.0f; accb = b;
        }
        if (b >= 0) acc += x[(size_t)i * D + d];
    }
    if (accb >= 0) atomicAdd(&graph_out[(size_t)accb * D + d], acc);
}

__global__ void gather1_kernel(const int* __restrict__ input_ids,
                               const int* __restrict__ table,
                               const float* __restrict__ x,
                               float* __restrict__ seq_out,
                               long long total, int D, int L) {
    long long t = (long long)blockIdx.x * blockDim.x + threadIdx.x;
    if (t >= total) return;
    long long row = t / D;
    int c = (int)(t - row * D);
    int b = (int)(row / L);
    int id = input_ids[row];
    int m  = (id >= 0 && id < ID_MAX) ? table[(size_t)b * ID_MAX + id] : INT_MAX;
    seq_out[t] = (m != INT_MAX) ? x[(long long)m * D + c] : 0.0f;
}

extern "C" void kernel_launch(void* const* d_in, const int* in_sizes, int n_in,
                              void* d_out, int out_size, void* d_ws, size_t ws_size,
                              hipStream_t stream) {
    const int*   input_ids  = (const int*)  d_in[0];   // [B, L]
    const int*   node_index = (const int*)  d_in[1];   // [N]
    const float* x          = (const float*)d_in[2];   // [N, D]
    const int*   ptr        = (const int*)  d_in[3];   // [B+1]

    const int BL = in_sizes[0];
    const int N  = in_sizes[1];
    const int D  = in_sizes[2] / N;
    const int B  = in_sizes[3] - 1;
    const int L  = BL / B;

    float* seq_out   = (float*)d_out;                    // [B*L*D]
    float* graph_out = (float*)d_out + (size_t)BL * D;   // [B*D]
    int*   table     = (int*)d_ws;                       // [B * ID_MAX]

    const int vpr = D >> 2;                              // float4 per row
    const bool vec_ok = ((D & 3) == 0) && (vpr > 0) && (vpr <= 256) &&
                        (256 % vpr == 0) && (B >= 1) && (B <= 63);

    if (vec_ok) {
        // K1: per-graph LDS table build + graph_out zero-init
        build_table_fused<<<B, 256, 0, stream>>>(node_index, ptr, table,
                                                 graph_out, D);

        // K2: fused pool + gather
        int vshift = 0;
        while ((1 << vshift) < vpr) ++vshift;            // vpr is a power of 2
        const int pool_blocks = 256;
        const int rows_pb = (N + pool_blocks - 1) / pool_blocks;
        const long long total_vec = (long long)BL * vpr;
        const int gather_blocks = (int)((total_vec + 255) / 256);
        pool_gather_fused<<<pool_blocks + gather_blocks, 256, 0, stream>>>(
            (const vf4*)x, ptr, input_ids, table, graph_out, (vf4*)seq_out,
            N, B, D, vpr, vshift, L, pool_blocks, rows_pb, total_vec);
    } else {
        const int table_n = B * ID_MAX;
        const int graph_n = B * D;
        const int init_n  = table_n > graph_n ? table_n : graph_n;
        init_kernel<<<(init_n + 255) / 256, 256, 0, stream>>>(table, graph_out,
                                                              table_n, graph_n);
        build_table_kernel<<<(N + 255) / 256, 256, 0, stream>>>(node_index, ptr,
                                                                table, N, B);
        const int rows_per_block = 128;
        const int nchunks = (N + rows_per_block - 1) / rows_per_block;
        int bs = D < 1024 ? ((D + 63) / 64) * 64 : 1024;
        pool1_kernel<<<nchunks, bs, 0, stream>>>(x, ptr, graph_out, N, B, D,
                                                 rows_per_block);
        const long long total = (long long)BL * D;
        const int blocks = (int)((total + 255) / 256);
        gather1_kernel<<<blocks, 256, 0, stream>>>(input_ids, table, x,
                                                   seq_out, total, D, L);
    }
}

// Round 4
// 104.066 us; speedup vs baseline: 1.0423x; 1.0423x over previous
//
#include <hip/hip_runtime.h>
#include <limits.h>

#define ID_MAX 4096

typedef float vf4 __attribute__((ext_vector_type(4)));

// ---------------------------------------------------------------------------
// K1: one block per graph, 1024 threads. Build first-occurrence table in LDS
// (atomicMin on LDS), flush to global table[b*ID_MAX..], zero graph_out.
// 1024 threads: LDS init/writeback in 4 iterations, node scan in 2 -- R3's
// 256-thread version serialized 16+16+6 iterations on only 16 CUs.
// ---------------------------------------------------------------------------
__global__ void __launch_bounds__(1024)
build_table_fused(const int* __restrict__ node_index,
                  const int* __restrict__ ptr,
                  int* __restrict__ table,
                  float* __restrict__ graph_out,
                  int D) {
    __shared__ int ltab[ID_MAX];
    const int b   = blockIdx.x;
    const int tid = threadIdx.x;
    const int start = ptr[b];
    const int end   = ptr[b + 1];

    for (int i = tid; i < ID_MAX; i += 1024) ltab[i] = INT_MAX;
    __syncthreads();

    for (int i = start + tid; i < end; i += 1024) {
        int id = node_index[i];
        if (id >= 0 && id < ID_MAX)
            atomicMin(&ltab[id], i - start);   // local position in graph b
    }
    __syncthreads();

    int* gt = table + (size_t)b * ID_MAX;
    for (int i = tid; i < ID_MAX; i += 1024) gt[i] = ltab[i];

    float* go = graph_out + (size_t)b * D;
    for (int i = tid; i < D; i += 1024) go[i] = 0.0f;
}

__device__ __forceinline__ int seg_search(const int* sptr, int B, int i) {
    if (i < sptr[0] || i >= sptr[B]) return -1;
    int lo = 0, hi = B;
    while (hi - lo > 1) {
        int mid = (lo + hi) >> 1;
        if (sptr[mid] <= i) lo = mid; else hi = mid;
    }
    return lo;
}

// ---------------------------------------------------------------------------
// K2: fused pool + gather in one grid so the two independent memory streams
// co-execute (stream-captured graphs serialize separate launches).
//   blocks [0, pool_blocks)   : segment-sum pool (float4, NT loads)
//   blocks [pool_blocks, ...) : table-lookup gather (float4, NT stores)
// ---------------------------------------------------------------------------
__global__ void pool_gather_fused(const vf4* __restrict__ x4,
                                  const int* __restrict__ ptr,
                                  const int* __restrict__ input_ids,
                                  const int* __restrict__ table,
                                  float* __restrict__ graph_out,
                                  vf4* __restrict__ out4,
                                  int N, int B, int D, int vpr, int vshift, int L,
                                  int pool_blocks, int rows_pb,
                                  long long total_vec) {
    const int tid = threadIdx.x;

    if ((int)blockIdx.x < pool_blocks) {
        // ---------------- pool ----------------
        __shared__ int sptr[64];
        __shared__ vf4 red[256];
        if (tid <= B) sptr[tid] = ptr[tid];
        __syncthreads();

        const int rows_per_iter = 256 / vpr;   // vpr divides 256 (host-checked)
        const int c    = tid & (vpr - 1);
        const int rsub = tid / vpr;

        const int r0 = blockIdx.x * rows_pb;
        const int r1 = min(r0 + rows_pb, N);
        if (r0 >= r1) return;

        const int b_first = seg_search(sptr, B, r0);
        const int b_last  = seg_search(sptr, B, r1 - 1);

        if (b_first == b_last && b_first >= 0) {
            // fast path: whole chunk inside one graph -> pure streaming
            vf4 acc = 0.0f;
            for (int i = r0 + rsub; i < r1; i += rows_per_iter)
                acc += __builtin_nontemporal_load(&x4[(size_t)i * vpr + c]);
            red[tid] = acc;
            __syncthreads();
            if (rsub == 0) {
                for (int k = 1; k < rows_per_iter; ++k)
                    acc += red[k * vpr + c];
                float* dst = &graph_out[(size_t)b_first * D + c * 4];
                atomicAdd(dst + 0, acc.x);
                atomicAdd(dst + 1, acc.y);
                atomicAdd(dst + 2, acc.z);
                atomicAdd(dst + 3, acc.w);
            }
        } else {
            // generic path: chunk crosses a boundary (~16 of 256 blocks)
            vf4 acc = 0.0f;
            int accb = -1;
            for (int i = r0 + rsub; i < r1; i += rows_per_iter) {
                int b = seg_search(sptr, B, i);
                if (b != accb) {
                    if (accb >= 0) {
                        float* dst = &graph_out[(size_t)accb * D + c * 4];
                        atomicAdd(dst + 0, acc.x);
                        atomicAdd(dst + 1, acc.y);
                        atomicAdd(dst + 2, acc.z);
                        atomicAdd(dst + 3, acc.w);
                    }
                    acc = 0.0f;
                    accb = b;
                }
                if (b >= 0) acc += x4[(size_t)i * vpr + c];
            }
            if (accb >= 0) {
                float* dst = &graph_out[(size_t)accb * D + c * 4];
                atomicAdd(dst + 0, acc.x);
                atomicAdd(dst + 1, acc.y);
                atomicAdd(dst + 2, acc.z);
                atomicAdd(dst + 3, acc.w);
            }
        }
    } else {
        // ---------------- gather ----------------
        long long t = (long long)(blockIdx.x - pool_blocks) * blockDim.x + tid;
        if (t >= total_vec) return;
        int row = (int)(t >> vshift);          // flattened (b,l)
        int c   = (int)(t & (vpr - 1));
        int b   = row / L;
        int id  = input_ids[row];
        int m   = (id >= 0 && id < ID_MAX) ? table[(size_t)b * ID_MAX + id]
                                           : INT_MAX;
        vf4 v = 0.0f;
        if (m != INT_MAX)
            v = x4[(long long)m * vpr + c];    // row m used GLOBALLY (faithful
                                               // to reference's local-as-global quirk)
        __builtin_nontemporal_store(v, &out4[t]);
    }
}

// ---------------------------------------------------------------------------
// Fallback kernels (odd D etc.)
// ---------------------------------------------------------------------------
__global__ void init_kernel(int* __restrict__ table, float* __restrict__ graph_out,
                            int table_n, int graph_n) {
    int i = blockIdx.x * blockDim.x + threadIdx.x;
    if (i < table_n) table[i] = INT_MAX;
    if (i < graph_n) graph_out[i] = 0.0f;
}

__global__ void build_table_kernel(const int* __restrict__ node_index,
                                   const int* __restrict__ ptr,
                                   int* __restrict__ table, int N, int B) {
    __shared__ int sptr[64];
    if (threadIdx.x <= B) sptr[threadIdx.x] = ptr[threadIdx.x];
    __syncthreads();
    int i = blockIdx.x * blockDim.x + threadIdx.x;
    if (i >= N) return;
    int b = seg_search(sptr, B, i);
    if (b < 0) return;
    int m = i - sptr[b];
    int id = node_index[i];
    if (id >= 0 && id < ID_MAX)
        atomicMin(&table[b * ID_MAX + id], m);
}

__global__ void pool1_kernel(const float* __restrict__ x,
                             const int* __restrict__ ptr,
                             float* __restrict__ graph_out,
                             int N, int B, int D, int rows_per_block) {
    __shared__ int sptr[64];
    if (threadIdx.x <= B) sptr[threadIdx.x] = ptr[threadIdx.x];
    __syncthreads();
    int d = threadIdx.x;
    if (d >= D) return;
    int r0 = blockIdx.x * rows_per_block;
    int r1 = min(r0 + rows_per_block, N);
    float acc = 0.0f;
    int accb = -1;
    for (int i = r0; i < r1; ++i) {
        int b = seg_search(sptr, B, i);
        if (b != accb) {
            if (accb >= 0) atomicAdd(&graph_out[(size_t)accb * D + d], acc);
            acc = 0.0f; accb = b;
        }
        if (b >= 0) acc += x[(size_t)i * D + d];
    }
    if (accb >= 0) atomicAdd(&graph_out[(size_t)accb * D + d], acc);
}

__global__ void gather1_kernel(const int* __restrict__ input_ids,
                               const int* __restrict__ table,
                               const float* __restrict__ x,
                               float* __restrict__ seq_out,
                               long long total, int D, int L) {
    long long t = (long long)blockIdx.x * blockDim.x + threadIdx.x;
    if (t >= total) return;
    long long row = t / D;
    int c = (int)(t - row * D);
    int b = (int)(row / L);
    int id = input_ids[row];
    int m  = (id >= 0 && id < ID_MAX) ? table[(size_t)b * ID_MAX + id] : INT_MAX;
    seq_out[t] = (m != INT_MAX) ? x[(long long)m * D + c] : 0.0f;
}

extern "C" void kernel_launch(void* const* d_in, const int* in_sizes, int n_in,
                              void* d_out, int out_size, void* d_ws, size_t ws_size,
                              hipStream_t stream) {
    const int*   input_ids  = (const int*)  d_in[0];   // [B, L]
    const int*   node_index = (const int*)  d_in[1];   // [N]
    const float* x          = (const float*)d_in[2];   // [N, D]
    const int*   ptr        = (const int*)  d_in[3];   // [B+1]

    const int BL = in_sizes[0];
    const int N  = in_sizes[1];
    const int D  = in_sizes[2] / N;
    const int B  = in_sizes[3] - 1;
    const int L  = BL / B;

    float* seq_out   = (float*)d_out;                    // [B*L*D]
    float* graph_out = (float*)d_out + (size_t)BL * D;   // [B*D]
    int*   table     = (int*)d_ws;                       // [B * ID_MAX]

    const int vpr = D >> 2;                              // float4 per row
    const bool vec_ok = ((D & 3) == 0) && (vpr > 0) && (vpr <= 256) &&
                        (256 % vpr == 0) && (B >= 1) && (B <= 63);

    if (vec_ok) {
        // K1: per-graph LDS table build + graph_out zero-init (1024 threads)
        build_table_fused<<<B, 1024, 0, stream>>>(node_index, ptr, table,
                                                  graph_out, D);

        // K2: fused pool + gather
        int vshift = 0;
        while ((1 << vshift) < vpr) ++vshift;            // vpr is a power of 2
        const int pool_blocks = 256;
        const int rows_pb = (N + pool_blocks - 1) / pool_blocks;
        const long long total_vec = (long long)BL * vpr;
        const int gather_blocks = (int)((total_vec + 255) / 256);
        pool_gather_fused<<<pool_blocks + gather_blocks, 256, 0, stream>>>(
            (const vf4*)x, ptr, input_ids, table, graph_out, (vf4*)seq_out,
            N, B, D, vpr, vshift, L, pool_blocks, rows_pb, total_vec);
    } else {
        const int table_n = B * ID_MAX;
        const int graph_n = B * D;
        const int init_n  = table_n > graph_n ? table_n : graph_n;
        init_kernel<<<(init_n + 255) / 256, 256, 0, stream>>>(table, graph_out,
                                                              table_n, graph_n);
        build_table_kernel<<<(N + 255) / 256, 256, 0, stream>>>(node_index, ptr,
                                                                table, N, B);
        const int rows_per_block = 128;
        const int nchunks = (N + rows_per_block - 1) / rows_per_block;
        int bs = D < 1024 ? ((D + 63) / 64) * 64 : 1024;
        pool1_kernel<<<nchunks, bs, 0, stream>>>(x, ptr, graph_out, N, B, D,
                                                 rows_per_block);
        const long long total = (long long)BL * D;
        const int blocks = (int)((total + 255) / 256);
        gather1_kernel<<<blocks, 256, 0, stream>>>(input_ids, table, x,
                                                   seq_out, total, D, L);
    }
}